// Round 1
// baseline (186.507 us; speedup 1.0000x reference)
//
#include <hip/hip_runtime.h>
#include <math.h>

#define T_  4
#define B_  16
#define C_  384
#define HW_ 256
#define E_  8

typedef __attribute__((ext_vector_type(8))) __bf16 bf16x8;
typedef __attribute__((ext_vector_type(4))) float f32x4;

union FragU { uint4 u; bf16x8 v; };

// taus = jnp.linspace(1.5, 4.0, 8) in fp32, endpoint exact
__device__ __forceinline__ float tau_of(int e) {
    if (e == 7) return 4.0f;
    const float delta = 2.5f / 7.0f;
    return __fadd_rn(1.5f, __fmul_rn((float)e, delta));
}

// bits of m (8 spikes) -> bf16x8 {0,1} fragment
__device__ __forceinline__ FragU expand_mask(unsigned m) {
    FragU f;
    f.u.x = ((m & 1u)   ? 0x3F80u : 0u) | ((m & 2u)   ? 0x3F800000u : 0u);
    f.u.y = ((m & 4u)   ? 0x3F80u : 0u) | ((m & 8u)   ? 0x3F800000u : 0u);
    f.u.z = ((m & 16u)  ? 0x3F80u : 0u) | ((m & 32u)  ? 0x3F800000u : 0u);
    f.u.w = ((m & 64u)  ? 0x3F80u : 0u) | ((m & 128u) ? 0x3F800000u : 0u);
    return f;
}

// ---------------- k_prep: fused weight-split + router LIF (unchanged) -------
__global__ __launch_bounds__(256) void k_prep(const float* __restrict__ x,
        const float* __restrict__ W1, const float* __restrict__ W2,
        unsigned short* __restrict__ Whif, unsigned short* __restrict__ Wlof,
        float* __restrict__ m) {
    if (blockIdx.x < 1152) {
        int tid = blockIdx.x * 256 + threadIdx.x;    // 294912 total
        int l = tid & 63;
        int f = tid >> 6;                            // 0..4607
        int osub = f % 24;
        int ksub = (f / 24) % 12;
        int cv = (f / 288) & 1;
        int e = f / 576;
        const float* Wsrc = (cv == 0 ? W1 : W2) + (size_t)e * C_ * C_;
        int o = osub * 16 + (l & 15);
        int c0 = ksub * 32 + (l >> 4) * 8;
        const float* src = Wsrc + (size_t)o * C_ + c0;
        unsigned hw[8], lw[8];
#pragma unroll
        for (int j = 0; j < 8; ++j) {
            float w = src[j];
            unsigned u = __float_as_uint(w);
            unsigned hi = (u + 0x7FFFu + ((u >> 16) & 1u)) >> 16;
            float hf = __uint_as_float(hi << 16);
            float res = __fsub_rn(w, hf);
            unsigned ru = __float_as_uint(res);
            unsigned lo = (ru + 0x7FFFu + ((ru >> 16) & 1u)) >> 16;
            hw[j] = hi & 0xFFFFu;
            lw[j] = lo & 0xFFFFu;
        }
        size_t dst = (size_t)f * 512 + (size_t)l * 8;
        uint4 hv = make_uint4(hw[0] | (hw[1] << 16), hw[2] | (hw[3] << 16),
                              hw[4] | (hw[5] << 16), hw[6] | (hw[7] << 16));
        uint4 lv = make_uint4(lw[0] | (lw[1] << 16), lw[2] | (lw[3] << 16),
                              lw[4] | (lw[5] << 16), lw[6] | (lw[7] << 16));
        *reinterpret_cast<uint4*>(Whif + dst) = hv;
        *reinterpret_cast<uint4*>(Wlof + dst) = lv;
    } else {
        int bc = blockIdx.x - 1152;
        int b = bc / C_, c = bc % C_;
        int p = threadIdx.x;
        int wv = threadIdx.x >> 6;
        __shared__ int cnt[T_][4];
        float v = 0.0f;
#pragma unroll
        for (int t = 0; t < T_; ++t) {
            float xv = x[((t * B_ + b) * C_ + c) * HW_ + p];
            v = __fadd_rn(v, __fdiv_rn(__fsub_rn(xv, v), 2.0f));
            bool s = (__fsub_rn(v, 1.0f) >= 0.0f);
            if (s) v = 0.0f;
            unsigned long long mask = __ballot(s);
            if ((threadIdx.x & 63) == 0) cnt[t][wv] = (int)__popcll(mask);
        }
        __syncthreads();
        if (threadIdx.x < T_) {
            int t = threadIdx.x;
            int tot = cnt[t][0] + cnt[t][1] + cnt[t][2] + cnt[t][3];
            m[(t * B_ + b) * C_ + c] = (float)tot * 0.00390625f;
        }
    }
}

// ---------------- conv core v2: B-frags via ds_read_b128 from LDS -----------
// sf holds pre-expanded bf16 {0,1} fragments: frag(ksub,t) at ksub*4096+t*1024,
// lane l owns bytes [l*16, l*16+16) => elements c = ksub*32+(l>>4)*8+j, col=l&15.
// acc is C-in/C-out (may be pre-initialized by the caller).
__device__ __forceinline__ void conv_mfma2(const unsigned short* __restrict__ Whif,
                                           const unsigned short* __restrict__ Wlof,
                                           unsigned base,
                                           const unsigned char* __restrict__ sf,
                                           f32x4 (&acc)[3][4],
                                           int wv, int lane) {
    const unsigned lane8 = (unsigned)lane * 8u;
    const unsigned wbase = base + (unsigned)(wv * 3) * 512u + lane8;
    const unsigned char* fp = sf + lane * 16;
    FragU c0f, c1f, c2f, n0f, n1f, n2f, bf[T_];
    c0f.u = *reinterpret_cast<const uint4*>(Wlof + wbase);
    c1f.u = *reinterpret_cast<const uint4*>(Wlof + wbase + 512u);
    c2f.u = *reinterpret_cast<const uint4*>(Wlof + wbase + 1024u);
#pragma unroll 1
    for (int ksub = 0; ksub < 12; ++ksub) {
        unsigned fo = wbase + (unsigned)ksub * 24u * 512u;
        const unsigned char* fk = fp + ksub * 4096;
#pragma unroll
        for (int t = 0; t < T_; ++t)
            bf[t].u = *reinterpret_cast<const uint4*>(fk + t * 1024);
        n0f.u = *reinterpret_cast<const uint4*>(Whif + fo);
        n1f.u = *reinterpret_cast<const uint4*>(Whif + fo + 512u);
        n2f.u = *reinterpret_cast<const uint4*>(Whif + fo + 1024u);
#pragma unroll
        for (int t = 0; t < T_; ++t) {
            acc[0][t] = __builtin_amdgcn_mfma_f32_16x16x32_bf16(c0f.v, bf[t].v, acc[0][t], 0, 0, 0);
            acc[1][t] = __builtin_amdgcn_mfma_f32_16x16x32_bf16(c1f.v, bf[t].v, acc[1][t], 0, 0, 0);
            acc[2][t] = __builtin_amdgcn_mfma_f32_16x16x32_bf16(c2f.v, bf[t].v, acc[2][t], 0, 0, 0);
        }
        if (ksub < 11) {
            unsigned fn = fo + 24u * 512u;
            c0f.u = *reinterpret_cast<const uint4*>(Wlof + fn);
            c1f.u = *reinterpret_cast<const uint4*>(Wlof + fn + 512u);
            c2f.u = *reinterpret_cast<const uint4*>(Wlof + fn + 1024u);
        }
#pragma unroll
        for (int t = 0; t < T_; ++t) {
            acc[0][t] = __builtin_amdgcn_mfma_f32_16x16x32_bf16(n0f.v, bf[t].v, acc[0][t], 0, 0, 0);
            acc[1][t] = __builtin_amdgcn_mfma_f32_16x16x32_bf16(n1f.v, bf[t].v, acc[1][t], 0, 0, 0);
            acc[2][t] = __builtin_amdgcn_mfma_f32_16x16x32_bf16(n2f.v, bf[t].v, acc[2][t], 0, 0, 0);
        }
    }
}

// ---------------- k_expert v2: rank-parallel 16-wave block ------------------
// grid 256 (b x ptile), 1024 threads (16 waves). waves 0-7: rank0, 8-15: rank1.
// Both ranks run concurrently; combine via LDS (unique writer, no atomics).
__global__ __launch_bounds__(1024, 4) void k_expert(
        const float* __restrict__ x, const float* __restrict__ m,
        const float* __restrict__ rW, const float* __restrict__ rb,
        const float* __restrict__ rbs, const float* __restrict__ rbb,
        const unsigned short* __restrict__ Whif, const unsigned short* __restrict__ Wlof,
        const float* __restrict__ b1, const float* __restrict__ s1sc, const float* __restrict__ s1bi,
        const float* __restrict__ b2, const float* __restrict__ s2sc, const float* __restrict__ s2bi,
        float* __restrict__ out) {
    int blk = blockIdx.x;
    int b = (blk & 7) | (((blk >> 3) & 1) << 3);
    int ptile = blk >> 4;

    // sfrag: per-rank expanded B fragments (48 KB each); reused as pcomb at end
    __shared__ __align__(16) unsigned char sfrag[2][49152];
    __shared__ float bns[2 * 7 * C_];    // [rank][A1,B1,BB1,A2,B2,BB2,rA2][o]
    __shared__ float lg[E_];
    __shared__ float wsl[2];
    __shared__ int esl[2];

    int tid = threadIdx.x;
    int wave = tid >> 6;          // 0..15
    int rank = wave >> 3;         // 0/1
    int wv = wave & 7;            // wave within rank group
    int rtid = tid & 511;         // thread within rank group
    int lane = tid & 63;
    int q = lane >> 4;
    int pl = lane & 15;
    int p = ptile * 16 + pl;
    float denom = sqrtf(__fadd_rn(1.0f, 1e-5f));

    // ---- inline route (wave 0), identical arithmetic to previous version
    if (tid < 64) {
        int combo = tid & 31, half = tid >> 5;
        int e = combo >> 2, t = combo & 3;
        float dot = 0.0f;
        int c0 = half * 192;
        for (int c = 0; c < 192; ++c)
            dot = fmaf(rW[e * C_ + c0 + c], m[(t * B_ + b) * C_ + c0 + c], dot);
        dot += __shfl_down(dot, 32);
        float Ar = __fdiv_rn(rbs[e], denom);
        float lt = __fadd_rn(__fmul_rn(__fadd_rn(dot, rb[e]), Ar), rbb[e]);
        lt = __fadd_rn(lt, __shfl_xor(lt, 1));
        lt = __fadd_rn(lt, __shfl_xor(lt, 2));
        if (half == 0 && t == 0) lg[e] = __fmul_rn(lt, 0.25f);
    }
    __syncthreads();
    if (tid == 0) {
        float pr[E_];
        float mx = lg[0];
        for (int i = 1; i < E_; ++i) mx = fmaxf(mx, lg[i]);
        float s = 0.0f;
        for (int i = 0; i < E_; ++i) { pr[i] = expf(__fsub_rn(lg[i], mx)); s = __fadd_rn(s, pr[i]); }
        for (int i = 0; i < E_; ++i) pr[i] = __fdiv_rn(pr[i], s);
        int i0 = 0;
        for (int i = 1; i < E_; ++i) if (pr[i] > pr[i0]) i0 = i;
        int i1 = (i0 == 0) ? 1 : 0;
        for (int i = 0; i < E_; ++i) if (i != i0 && pr[i] > pr[i1]) i1 = i;
        float s2 = __fadd_rn(pr[i0], pr[i1]);
        wsl[0] = __fdiv_rn(pr[i0], s2);
        wsl[1] = __fdiv_rn(pr[i1], s2);
        esl[0] = i0;
        esl[1] = i1;
    }
    __syncthreads();

    int er = esl[rank];
    float wr = wsl[rank];
    float taur = tau_of(er);

    // ---- BN staging (own rank)
    if (rtid < C_) {
        float* bp = bns + rank * 7 * C_;
        float a1 = __fdiv_rn(s1sc[er * C_ + rtid], denom);
        float a2 = __fdiv_rn(s2sc[er * C_ + rtid], denom);
        bp[0 * C_ + rtid] = a1;
        bp[1 * C_ + rtid] = b1[er * C_ + rtid];
        bp[2 * C_ + rtid] = s1bi[er * C_ + rtid];
        bp[3 * C_ + rtid] = a2;
        bp[4 * C_ + rtid] = b2[er * C_ + rtid];
        bp[5 * C_ + rtid] = s2bi[er * C_ + rtid];
        bp[6 * C_ + rtid] = __fdiv_rn(1.0f, a2);   // rA2 (acc-fold; scales=1 in dataset)
    }

    // ---- LIF1 (own rank, own tau): write expanded bf16 frags straight to LDS
    unsigned char* sf = &sfrag[rank][0];
#pragma unroll 1
    for (int task = rtid; task < 48 * 16; task += 512) {
        int cb = task >> 4;          // c-group of 8: 0..47
        int tpl = task & 15;
        int tp = ptile * 16 + tpl;
        unsigned char* dst = sf + (cb >> 2) * 4096 + (((cb & 3) * 16 + tpl) * 16);
        float v[8];
#pragma unroll
        for (int j = 0; j < 8; ++j) v[j] = 0.0f;
#pragma unroll
        for (int t = 0; t < T_; ++t) {
            int gbase = ((t * B_ + b) * C_ + cb * 8) * HW_ + tp;
            unsigned d0 = 0, d1 = 0, d2 = 0, d3 = 0;
#pragma unroll
            for (int j = 0; j < 8; ++j) {
                float xv = x[gbase + j * HW_];
                v[j] = __fadd_rn(v[j], __fdiv_rn(__fsub_rn(xv, v[j]), taur));
                bool s = (__fsub_rn(v[j], 1.0f) >= 0.0f);
                if (s) v[j] = 0.0f;
                unsigned bitv = s ? ((j & 1) ? 0x3F800000u : 0x3F80u) : 0u;
                if (j < 2) d0 |= bitv;
                else if (j < 4) d1 |= bitv;
                else if (j < 6) d2 |= bitv;
                else d3 |= bitv;
            }
            *reinterpret_cast<uint4*>(dst + t * 1024) = make_uint4(d0, d1, d2, d3);
        }
    }
    __syncthreads();

    // ---- conv1 (own rank)
    f32x4 acc[3][T_];
#pragma unroll
    for (int os = 0; os < 3; ++os)
#pragma unroll
        for (int t = 0; t < T_; ++t) acc[os][t] = (f32x4)0.0f;
    unsigned base1 = (unsigned)(er * 2) * 12u * 24u * 512u;
    conv_mfma2(Whif, Wlof, base1, sf, acc, wv, lane);

    // ---- epi1: h = x + bn1(y); LIF2 bits; acc := h * rA2 (fold into conv2 C-in)
    const float* bp = bns + rank * 7 * C_;
    unsigned pk[3];
#pragma unroll
    for (int os = 0; os < 3; ++os) {
        float v2s[4] = {0.f, 0.f, 0.f, 0.f};
        unsigned pkos = 0;
#pragma unroll
        for (int t = 0; t < T_; ++t) {
            unsigned nb = 0;
#pragma unroll
            for (int r = 0; r < 4; ++r) {
                int o = wv * 48 + os * 16 + q * 4 + r;
                int gi = ((t * B_ + b) * C_ + o) * HW_ + p;
                float y = acc[os][t][r];
                float h = __fadd_rn(x[gi],
                    __fadd_rn(__fmul_rn(__fadd_rn(y, bp[1 * C_ + o]), bp[0 * C_ + o]),
                              bp[2 * C_ + o]));
                v2s[r] = __fadd_rn(v2s[r], __fdiv_rn(__fsub_rn(h, v2s[r]), taur));
                if (__fsub_rn(v2s[r], 1.0f) >= 0.0f) { nb |= (1u << r); v2s[r] = 0.f; }
                acc[os][t][r] = __fmul_rn(h, bp[6 * C_ + o]);
            }
            unsigned nb_hi = (unsigned)__shfl_down((int)nb, 16);
            pkos |= ((nb | (nb_hi << 4)) & 0xFFu) << (8 * t);
        }
        pk[os] = pkos;
    }
    __syncthreads();   // all conv1 reads of sf complete before overwrite

    // ---- write s2 frags (even-q threads own full bytes)
    if ((q & 1) == 0) {
#pragma unroll
        for (int os = 0; os < 3; ++os) {
            int g = wv * 6 + os * 2 + (q >> 1);      // c-group of 8 for conv2 B
            unsigned char* dst = sf + (g >> 2) * 4096 + (((g & 3) * 16 + pl) * 16);
#pragma unroll
            for (int t = 0; t < T_; ++t) {
                FragU f = expand_mask((pk[os] >> (8 * t)) & 0xFFu);
                *reinterpret_cast<uint4*>(dst + t * 1024) = f.u;
            }
        }
    }
    __syncthreads();

    // ---- conv2 (acc carries folded residual)
    unsigned base2 = (unsigned)(er * 2 + 1) * 12u * 24u * 512u;
    conv_mfma2(Whif, Wlof, base2, sf, acc, wv, lane);

    __syncthreads();   // all conv2 reads of sf complete; sfrag becomes pcomb

    // ---- epi2 + rank combine: val = (acc + B2)*A2 + BB2  (= bn2(y2) + h)
    float* pcomb = reinterpret_cast<float*>(&sfrag[0][0]);   // [t][o][pl], 96 KB
    if (rank == 0) {
#pragma unroll
        for (int os = 0; os < 3; ++os)
#pragma unroll
            for (int t = 0; t < T_; ++t)
#pragma unroll
                for (int r = 0; r < 4; ++r) {
                    int o = wv * 48 + os * 16 + q * 4 + r;
                    float y = acc[os][t][r];
                    float val = __fadd_rn(__fmul_rn(__fadd_rn(y, bp[4 * C_ + o]),
                                                    bp[3 * C_ + o]),
                                          bp[5 * C_ + o]);
                    pcomb[(t * C_ + o) * 16 + pl] = __fmul_rn(wr, val);
                }
    }
    __syncthreads();
    if (rank == 1) {
#pragma unroll
        for (int os = 0; os < 3; ++os)
#pragma unroll
            for (int t = 0; t < T_; ++t)
#pragma unroll
                for (int r = 0; r < 4; ++r) {
                    int o = wv * 48 + os * 16 + q * 4 + r;
                    int gi = ((t * B_ + b) * C_ + o) * HW_ + p;
                    float y = acc[os][t][r];
                    float val = __fadd_rn(__fmul_rn(__fadd_rn(y, bp[4 * C_ + o]),
                                                    bp[3 * C_ + o]),
                                          bp[5 * C_ + o]);
                    out[gi] = __fadd_rn(pcomb[(t * C_ + o) * 16 + pl],
                                        __fmul_rn(wr, val));
                }
    }
}

extern "C" void kernel_launch(void* const* d_in, const int* in_sizes, int n_in,
                              void* d_out, int out_size, void* d_ws, size_t ws_size,
                              hipStream_t stream) {
    const float* x    = (const float*)d_in[0];
    const float* rW   = (const float*)d_in[1];
    const float* rb   = (const float*)d_in[2];
    const float* rbs  = (const float*)d_in[3];
    const float* rbb  = (const float*)d_in[4];
    const float* W1   = (const float*)d_in[5];
    const float* b1   = (const float*)d_in[6];
    const float* s1sc = (const float*)d_in[7];
    const float* s1bi = (const float*)d_in[8];
    const float* W2   = (const float*)d_in[9];
    const float* b2   = (const float*)d_in[10];
    const float* s2sc = (const float*)d_in[11];
    const float* s2bi = (const float*)d_in[12];
    float* out = (float*)d_out;

    // ws layout: Whif (4718592 B) | Wlof (4718592 B) | m (24576 floats)
    unsigned short* Whif = (unsigned short*)d_ws;
    unsigned short* Wlof = Whif + 2359296;
    float* m = (float*)((char*)d_ws + 9437184);

    hipLaunchKernelGGL(k_prep, dim3(1152 + B_ * C_), dim3(256), 0, stream,
                       x, W1, W2, Whif, Wlof, m);
    hipLaunchKernelGGL(k_expert, dim3(256), dim3(1024), 0, stream,
                       x, m, rW, rb, rbs, rbb, Whif, Wlof,
                       b1, s1sc, s1bi, b2, s2sc, s2bi, out);
}

// Round 2
// 186.272 us; speedup vs baseline: 1.0013x; 1.0013x over previous
//
#include <hip/hip_runtime.h>
#include <math.h>

#define T_  4
#define B_  16
#define C_  384
#define HW_ 256
#define E_  8

typedef __attribute__((ext_vector_type(8))) __bf16 bf16x8;
typedef __attribute__((ext_vector_type(4))) float f32x4;

union FragU { uint4 u; bf16x8 v; };

// taus = jnp.linspace(1.5, 4.0, 8) in fp32, endpoint exact
__device__ __forceinline__ float tau_of(int e) {
    if (e == 7) return 4.0f;
    const float delta = 2.5f / 7.0f;
    return __fadd_rn(1.5f, __fmul_rn((float)e, delta));
}

// bits of m (8 spikes) -> bf16x8 {0,1} fragment
__device__ __forceinline__ FragU expand_mask(unsigned m) {
    FragU f;
    f.u.x = ((m & 1u)   ? 0x3F80u : 0u) | ((m & 2u)   ? 0x3F800000u : 0u);
    f.u.y = ((m & 4u)   ? 0x3F80u : 0u) | ((m & 8u)   ? 0x3F800000u : 0u);
    f.u.z = ((m & 16u)  ? 0x3F80u : 0u) | ((m & 32u)  ? 0x3F800000u : 0u);
    f.u.w = ((m & 64u)  ? 0x3F80u : 0u) | ((m & 128u) ? 0x3F800000u : 0u);
    return f;
}

// ---------------- k_prep: fused weight-split + router LIF (unchanged) -------
__global__ __launch_bounds__(256) void k_prep(const float* __restrict__ x,
        const float* __restrict__ W1, const float* __restrict__ W2,
        unsigned short* __restrict__ Whif, unsigned short* __restrict__ Wlof,
        float* __restrict__ m) {
    if (blockIdx.x < 1152) {
        int tid = blockIdx.x * 256 + threadIdx.x;    // 294912 total
        int l = tid & 63;
        int f = tid >> 6;                            // 0..4607
        int osub = f % 24;
        int ksub = (f / 24) % 12;
        int cv = (f / 288) & 1;
        int e = f / 576;
        const float* Wsrc = (cv == 0 ? W1 : W2) + (size_t)e * C_ * C_;
        int o = osub * 16 + (l & 15);
        int c0 = ksub * 32 + (l >> 4) * 8;
        const float* src = Wsrc + (size_t)o * C_ + c0;
        unsigned hw[8], lw[8];
#pragma unroll
        for (int j = 0; j < 8; ++j) {
            float w = src[j];
            unsigned u = __float_as_uint(w);
            unsigned hi = (u + 0x7FFFu + ((u >> 16) & 1u)) >> 16;
            float hf = __uint_as_float(hi << 16);
            float res = __fsub_rn(w, hf);
            unsigned ru = __float_as_uint(res);
            unsigned lo = (ru + 0x7FFFu + ((ru >> 16) & 1u)) >> 16;
            hw[j] = hi & 0xFFFFu;
            lw[j] = lo & 0xFFFFu;
        }
        size_t dst = (size_t)f * 512 + (size_t)l * 8;
        uint4 hv = make_uint4(hw[0] | (hw[1] << 16), hw[2] | (hw[3] << 16),
                              hw[4] | (hw[5] << 16), hw[6] | (hw[7] << 16));
        uint4 lv = make_uint4(lw[0] | (lw[1] << 16), lw[2] | (lw[3] << 16),
                              lw[4] | (lw[5] << 16), lw[6] | (lw[7] << 16));
        *reinterpret_cast<uint4*>(Whif + dst) = hv;
        *reinterpret_cast<uint4*>(Wlof + dst) = lv;
    } else {
        int bc = blockIdx.x - 1152;
        int b = bc / C_, c = bc % C_;
        int p = threadIdx.x;
        int wv = threadIdx.x >> 6;
        __shared__ int cnt[T_][4];
        float v = 0.0f;
#pragma unroll
        for (int t = 0; t < T_; ++t) {
            float xv = x[((t * B_ + b) * C_ + c) * HW_ + p];
            v = __fadd_rn(v, __fdiv_rn(__fsub_rn(xv, v), 2.0f));
            bool s = (__fsub_rn(v, 1.0f) >= 0.0f);
            if (s) v = 0.0f;
            unsigned long long mask = __ballot(s);
            if ((threadIdx.x & 63) == 0) cnt[t][wv] = (int)__popcll(mask);
        }
        __syncthreads();
        if (threadIdx.x < T_) {
            int t = threadIdx.x;
            int tot = cnt[t][0] + cnt[t][1] + cnt[t][2] + cnt[t][3];
            m[(t * B_ + b) * C_ + c] = (float)tot * 0.00390625f;
        }
    }
}

// ---------------- conv core v2: B-frags via ds_read_b128 from LDS -----------
// sf holds pre-expanded bf16 {0,1} fragments: frag(ksub,t) at ksub*4096+t*1024,
// lane l owns bytes [l*16, l*16+16) => elements c = ksub*32+(l>>4)*8+j, col=l&15.
// acc is C-in/C-out (may be pre-initialized by the caller).
__device__ __forceinline__ void conv_mfma2(const unsigned short* __restrict__ Whif,
                                           const unsigned short* __restrict__ Wlof,
                                           unsigned base,
                                           const unsigned char* __restrict__ sf,
                                           f32x4 (&acc)[3][4],
                                           int wv, int lane) {
    const unsigned lane8 = (unsigned)lane * 8u;
    const unsigned wbase = base + (unsigned)(wv * 3) * 512u + lane8;
    const unsigned char* fp = sf + lane * 16;
    FragU c0f, c1f, c2f, n0f, n1f, n2f, bf[T_];
    c0f.u = *reinterpret_cast<const uint4*>(Wlof + wbase);
    c1f.u = *reinterpret_cast<const uint4*>(Wlof + wbase + 512u);
    c2f.u = *reinterpret_cast<const uint4*>(Wlof + wbase + 1024u);
#pragma unroll 1
    for (int ksub = 0; ksub < 12; ++ksub) {
        unsigned fo = wbase + (unsigned)ksub * 24u * 512u;
        const unsigned char* fk = fp + ksub * 4096;
#pragma unroll
        for (int t = 0; t < T_; ++t)
            bf[t].u = *reinterpret_cast<const uint4*>(fk + t * 1024);
        n0f.u = *reinterpret_cast<const uint4*>(Whif + fo);
        n1f.u = *reinterpret_cast<const uint4*>(Whif + fo + 512u);
        n2f.u = *reinterpret_cast<const uint4*>(Whif + fo + 1024u);
#pragma unroll
        for (int t = 0; t < T_; ++t) {
            acc[0][t] = __builtin_amdgcn_mfma_f32_16x16x32_bf16(c0f.v, bf[t].v, acc[0][t], 0, 0, 0);
            acc[1][t] = __builtin_amdgcn_mfma_f32_16x16x32_bf16(c1f.v, bf[t].v, acc[1][t], 0, 0, 0);
            acc[2][t] = __builtin_amdgcn_mfma_f32_16x16x32_bf16(c2f.v, bf[t].v, acc[2][t], 0, 0, 0);
        }
        if (ksub < 11) {
            unsigned fn = fo + 24u * 512u;
            c0f.u = *reinterpret_cast<const uint4*>(Wlof + fn);
            c1f.u = *reinterpret_cast<const uint4*>(Wlof + fn + 512u);
            c2f.u = *reinterpret_cast<const uint4*>(Wlof + fn + 1024u);
        }
#pragma unroll
        for (int t = 0; t < T_; ++t) {
            acc[0][t] = __builtin_amdgcn_mfma_f32_16x16x32_bf16(n0f.v, bf[t].v, acc[0][t], 0, 0, 0);
            acc[1][t] = __builtin_amdgcn_mfma_f32_16x16x32_bf16(n1f.v, bf[t].v, acc[1][t], 0, 0, 0);
            acc[2][t] = __builtin_amdgcn_mfma_f32_16x16x32_bf16(n2f.v, bf[t].v, acc[2][t], 0, 0, 0);
        }
    }
}

// ---------------- k_expert v2.1: rank-parallel 16-wave block ----------------
// grid 256 (b x ptile), 1024 threads (16 waves). waves 0-7: rank0, 8-15: rank1.
// launch_bounds (1024, 1): one 16-wave block/CU -> 128-reg cap, no spill
// (the (1024,4) variant was interpreted as min-blocks -> 64-VGPR clamp -> spills).
__global__ __launch_bounds__(1024, 1) void k_expert(
        const float* __restrict__ x, const float* __restrict__ m,
        const float* __restrict__ rW, const float* __restrict__ rb,
        const float* __restrict__ rbs, const float* __restrict__ rbb,
        const unsigned short* __restrict__ Whif, const unsigned short* __restrict__ Wlof,
        const float* __restrict__ b1, const float* __restrict__ s1sc, const float* __restrict__ s1bi,
        const float* __restrict__ b2, const float* __restrict__ s2sc, const float* __restrict__ s2bi,
        float* __restrict__ out) {
    int blk = blockIdx.x;
    int b = (blk & 7) | (((blk >> 3) & 1) << 3);
    int ptile = blk >> 4;

    // sfrag: per-rank expanded B fragments (48 KB each); reused as pcomb at end
    __shared__ __align__(16) unsigned char sfrag[2][49152];
    __shared__ float bns[2 * 7 * C_];    // [rank][A1,B1,BB1,A2,B2,BB2,rA2][o]
    __shared__ float lg[E_];
    __shared__ float wsl[2];
    __shared__ int esl[2];

    int tid = threadIdx.x;
    int wave = tid >> 6;          // 0..15
    int rank = wave >> 3;         // 0/1
    int wv = wave & 7;            // wave within rank group
    int rtid = tid & 511;         // thread within rank group
    int lane = tid & 63;
    int q = lane >> 4;
    int pl = lane & 15;
    int p = ptile * 16 + pl;
    float denom = sqrtf(__fadd_rn(1.0f, 1e-5f));

    // ---- inline route (wave 0), identical arithmetic to previous version
    if (tid < 64) {
        int combo = tid & 31, half = tid >> 5;
        int e = combo >> 2, t = combo & 3;
        float dot = 0.0f;
        int c0 = half * 192;
        for (int c = 0; c < 192; ++c)
            dot = fmaf(rW[e * C_ + c0 + c], m[(t * B_ + b) * C_ + c0 + c], dot);
        dot += __shfl_down(dot, 32);
        float Ar = __fdiv_rn(rbs[e], denom);
        float lt = __fadd_rn(__fmul_rn(__fadd_rn(dot, rb[e]), Ar), rbb[e]);
        lt = __fadd_rn(lt, __shfl_xor(lt, 1));
        lt = __fadd_rn(lt, __shfl_xor(lt, 2));
        if (half == 0 && t == 0) lg[e] = __fmul_rn(lt, 0.25f);
    }
    __syncthreads();
    if (tid == 0) {
        float pr[E_];
        float mx = lg[0];
        for (int i = 1; i < E_; ++i) mx = fmaxf(mx, lg[i]);
        float s = 0.0f;
        for (int i = 0; i < E_; ++i) { pr[i] = expf(__fsub_rn(lg[i], mx)); s = __fadd_rn(s, pr[i]); }
        for (int i = 0; i < E_; ++i) pr[i] = __fdiv_rn(pr[i], s);
        int i0 = 0;
        for (int i = 1; i < E_; ++i) if (pr[i] > pr[i0]) i0 = i;
        int i1 = (i0 == 0) ? 1 : 0;
        for (int i = 0; i < E_; ++i) if (i != i0 && pr[i] > pr[i1]) i1 = i;
        float s2 = __fadd_rn(pr[i0], pr[i1]);
        wsl[0] = __fdiv_rn(pr[i0], s2);
        wsl[1] = __fdiv_rn(pr[i1], s2);
        esl[0] = i0;
        esl[1] = i1;
    }
    __syncthreads();

    int er = esl[rank];
    float wr = wsl[rank];
    float taur = tau_of(er);

    // ---- BN staging (own rank)
    if (rtid < C_) {
        float* bp = bns + rank * 7 * C_;
        float a1 = __fdiv_rn(s1sc[er * C_ + rtid], denom);
        float a2 = __fdiv_rn(s2sc[er * C_ + rtid], denom);
        bp[0 * C_ + rtid] = a1;
        bp[1 * C_ + rtid] = b1[er * C_ + rtid];
        bp[2 * C_ + rtid] = s1bi[er * C_ + rtid];
        bp[3 * C_ + rtid] = a2;
        bp[4 * C_ + rtid] = b2[er * C_ + rtid];
        bp[5 * C_ + rtid] = s2bi[er * C_ + rtid];
        bp[6 * C_ + rtid] = __fdiv_rn(1.0f, a2);   // rA2 (acc-fold; scales=1 in dataset)
    }

    // ---- LIF1 (own rank, own tau): write expanded bf16 frags straight to LDS
    unsigned char* sf = &sfrag[rank][0];
#pragma unroll 1
    for (int task = rtid; task < 48 * 16; task += 512) {
        int cb = task >> 4;          // c-group of 8: 0..47
        int tpl = task & 15;
        int tp = ptile * 16 + tpl;
        unsigned char* dst = sf + (cb >> 2) * 4096 + (((cb & 3) * 16 + tpl) * 16);
        float v[8];
#pragma unroll
        for (int j = 0; j < 8; ++j) v[j] = 0.0f;
#pragma unroll
        for (int t = 0; t < T_; ++t) {
            int gbase = ((t * B_ + b) * C_ + cb * 8) * HW_ + tp;
            unsigned d0 = 0, d1 = 0, d2 = 0, d3 = 0;
#pragma unroll
            for (int j = 0; j < 8; ++j) {
                float xv = x[gbase + j * HW_];
                v[j] = __fadd_rn(v[j], __fdiv_rn(__fsub_rn(xv, v[j]), taur));
                bool s = (__fsub_rn(v[j], 1.0f) >= 0.0f);
                if (s) v[j] = 0.0f;
                unsigned bitv = s ? ((j & 1) ? 0x3F800000u : 0x3F80u) : 0u;
                if (j < 2) d0 |= bitv;
                else if (j < 4) d1 |= bitv;
                else if (j < 6) d2 |= bitv;
                else d3 |= bitv;
            }
            *reinterpret_cast<uint4*>(dst + t * 1024) = make_uint4(d0, d1, d2, d3);
        }
    }
    __syncthreads();

    // ---- conv1 (own rank)
    f32x4 acc[3][T_];
#pragma unroll
    for (int os = 0; os < 3; ++os)
#pragma unroll
        for (int t = 0; t < T_; ++t) acc[os][t] = (f32x4)0.0f;
    unsigned base1 = (unsigned)(er * 2) * 12u * 24u * 512u;
    conv_mfma2(Whif, Wlof, base1, sf, acc, wv, lane);

    // ---- epi1: h = x + bn1(y); LIF2 bits; acc := h * rA2 (fold into conv2 C-in)
    const float* bp = bns + rank * 7 * C_;
    unsigned pk[3];
#pragma unroll
    for (int os = 0; os < 3; ++os) {
        float v2s[4] = {0.f, 0.f, 0.f, 0.f};
        unsigned pkos = 0;
#pragma unroll
        for (int t = 0; t < T_; ++t) {
            unsigned nb = 0;
#pragma unroll
            for (int r = 0; r < 4; ++r) {
                int o = wv * 48 + os * 16 + q * 4 + r;
                int gi = ((t * B_ + b) * C_ + o) * HW_ + p;
                float y = acc[os][t][r];
                float h = __fadd_rn(x[gi],
                    __fadd_rn(__fmul_rn(__fadd_rn(y, bp[1 * C_ + o]), bp[0 * C_ + o]),
                              bp[2 * C_ + o]));
                v2s[r] = __fadd_rn(v2s[r], __fdiv_rn(__fsub_rn(h, v2s[r]), taur));
                if (__fsub_rn(v2s[r], 1.0f) >= 0.0f) { nb |= (1u << r); v2s[r] = 0.f; }
                acc[os][t][r] = __fmul_rn(h, bp[6 * C_ + o]);
            }
            unsigned nb_hi = (unsigned)__shfl_down((int)nb, 16);
            pkos |= ((nb | (nb_hi << 4)) & 0xFFu) << (8 * t);
        }
        pk[os] = pkos;
    }
    __syncthreads();   // all conv1 reads of sf complete before overwrite

    // ---- write s2 frags (even-q threads own full bytes)
    if ((q & 1) == 0) {
#pragma unroll
        for (int os = 0; os < 3; ++os) {
            int g = wv * 6 + os * 2 + (q >> 1);      // c-group of 8 for conv2 B
            unsigned char* dst = sf + (g >> 2) * 4096 + (((g & 3) * 16 + pl) * 16);
#pragma unroll
            for (int t = 0; t < T_; ++t) {
                FragU f = expand_mask((pk[os] >> (8 * t)) & 0xFFu);
                *reinterpret_cast<uint4*>(dst + t * 1024) = f.u;
            }
        }
    }
    __syncthreads();

    // ---- conv2 (acc carries folded residual)
    unsigned base2 = (unsigned)(er * 2 + 1) * 12u * 24u * 512u;
    conv_mfma2(Whif, Wlof, base2, sf, acc, wv, lane);

    __syncthreads();   // all conv2 reads of sf complete; sfrag becomes pcomb

    // ---- epi2 + rank combine: val = (acc + B2)*A2 + BB2  (= bn2(y2) + h)
    float* pcomb = reinterpret_cast<float*>(&sfrag[0][0]);   // [t][o][pl], 96 KB
    if (rank == 0) {
#pragma unroll
        for (int os = 0; os < 3; ++os)
#pragma unroll
            for (int t = 0; t < T_; ++t)
#pragma unroll
                for (int r = 0; r < 4; ++r) {
                    int o = wv * 48 + os * 16 + q * 4 + r;
                    float y = acc[os][t][r];
                    float val = __fadd_rn(__fmul_rn(__fadd_rn(y, bp[4 * C_ + o]),
                                                    bp[3 * C_ + o]),
                                          bp[5 * C_ + o]);
                    pcomb[(t * C_ + o) * 16 + pl] = __fmul_rn(wr, val);
                }
    }
    __syncthreads();
    if (rank == 1) {
#pragma unroll
        for (int os = 0; os < 3; ++os)
#pragma unroll
            for (int t = 0; t < T_; ++t)
#pragma unroll
                for (int r = 0; r < 4; ++r) {
                    int o = wv * 48 + os * 16 + q * 4 + r;
                    int gi = ((t * B_ + b) * C_ + o) * HW_ + p;
                    float y = acc[os][t][r];
                    float val = __fadd_rn(__fmul_rn(__fadd_rn(y, bp[4 * C_ + o]),
                                                    bp[3 * C_ + o]),
                                          bp[5 * C_ + o]);
                    out[gi] = __fadd_rn(pcomb[(t * C_ + o) * 16 + pl],
                                        __fmul_rn(wr, val));
                }
    }
}

extern "C" void kernel_launch(void* const* d_in, const int* in_sizes, int n_in,
                              void* d_out, int out_size, void* d_ws, size_t ws_size,
                              hipStream_t stream) {
    const float* x    = (const float*)d_in[0];
    const float* rW   = (const float*)d_in[1];
    const float* rb   = (const float*)d_in[2];
    const float* rbs  = (const float*)d_in[3];
    const float* rbb  = (const float*)d_in[4];
    const float* W1   = (const float*)d_in[5];
    const float* b1   = (const float*)d_in[6];
    const float* s1sc = (const float*)d_in[7];
    const float* s1bi = (const float*)d_in[8];
    const float* W2   = (const float*)d_in[9];
    const float* b2   = (const float*)d_in[10];
    const float* s2sc = (const float*)d_in[11];
    const float* s2bi = (const float*)d_in[12];
    float* out = (float*)d_out;

    // ws layout: Whif (4718592 B) | Wlof (4718592 B) | m (24576 floats)
    unsigned short* Whif = (unsigned short*)d_ws;
    unsigned short* Wlof = Whif + 2359296;
    float* m = (float*)((char*)d_ws + 9437184);

    hipLaunchKernelGGL(k_prep, dim3(1152 + B_ * C_), dim3(256), 0, stream,
                       x, W1, W2, Whif, Wlof, m);
    hipLaunchKernelGGL(k_expert, dim3(256), dim3(1024), 0, stream,
                       x, m, rW, rb, rbs, rbb, Whif, Wlof,
                       b1, s1sc, s1bi, b2, s2sc, s2bi, out);
}